// Round 1
// baseline (3241.930 us; speedup 1.0000x reference)
//
#include <hip/hip_runtime.h>
#include <hip/hip_bf16.h>
#include <cstdint>
#include <cstddef>

#define B_    16
#define LQ    30
#define LD    1100
#define DIM   768
#define NH    12
#define DH_   64
#define WINSZ 11
#define WNUM  100
#define BC    2      // batches per chunk

// ---------------------------------------------------------------------------
// prep_q: Xq[b*30+l, e] = emb[q[b,l], e] * q_mask[b,l] * 0.125   (Dh^-0.5 folded)
// ---------------------------------------------------------------------------
__global__ __launch_bounds__(256) void prep_q_kernel(const int* __restrict__ q,
    const float* __restrict__ qmask, const float* __restrict__ emb,
    float* __restrict__ Xq) {
  int idx = blockIdx.x * 256 + threadIdx.x;       // over 480 * 192 float4s
  if (idx >= B_ * LQ * (DIM / 4)) return;
  int row = idx / (DIM / 4);
  int c4  = idx % (DIM / 4);
  int tok = q[row];
  float m = qmask[row] * 0.125f;
  float4 v = *reinterpret_cast<const float4*>(emb + (size_t)tok * DIM + c4 * 4);
  v.x *= m; v.y *= m; v.z *= m; v.w *= m;
  *reinterpret_cast<float4*>(Xq + (size_t)row * DIM + c4 * 4) = v;
}

// ---------------------------------------------------------------------------
// prep_d: X[r, e] = (emb[didx[b0*LD+r], e] * sqrt(D) + pe[r%LD, e]) * mask
//          (pe applied only if *peflag). One thread per (row, even/odd pair).
// ---------------------------------------------------------------------------
__global__ __launch_bounds__(256) void prep_d_kernel(const int* __restrict__ didx,
    const float* __restrict__ dmask, const float* __restrict__ emb,
    const int* __restrict__ peflag, float* __restrict__ X, int b0) {
  const int rows = BC * LD;
  int idx = blockIdx.x * 256 + threadIdx.x;       // rows * 384 pairs
  if (idx >= rows * (DIM / 2)) return;
  int r  = idx / (DIM / 2);
  int pc = idx % (DIM / 2);                       // pair index == i in div formula
  int grow = b0 * LD + r;
  int t = r % LD;                                 // position within document
  int tok = didx[grow];
  float m = dmask[grow];
  float2 v = *reinterpret_cast<const float2*>(emb + (size_t)tok * DIM + pc * 2);
  if (peflag[0]) {
    float div = expf(-0.023985261387f * (float)pc);   // 2i * (-ln(10000)/768)
    float ang = (float)t * div;
    float s, c;
    sincosf(ang, &s, &c);
    v.x = v.x * 27.712812921102035f + s;          // sqrt(768)
    v.y = v.y * 27.712812921102035f + c;
  }
  v.x *= m; v.y *= m;
  *reinterpret_cast<float2*>(X + (size_t)r * DIM + pc * 2) = v;
}

// ---------------------------------------------------------------------------
// gemm_bt_f32: C[M,N] = A[M,K] @ Wt[N,K]^T   (all row-major fp32)
// 64x64 tile, BK=16, 256 threads, 4x4 micro-tile per thread.
// N, K must be multiples of 64/16 (here N=K=768); M arbitrary (guarded).
// ---------------------------------------------------------------------------
__global__ __launch_bounds__(256) void gemm_bt_f32(const float* __restrict__ A,
    const float* __restrict__ Wt, float* __restrict__ C,
    int M, int N, int K) {
  __shared__ float As[16][64];
  __shared__ float Bs[16][64];
  int tid = threadIdx.x;
  int tx = tid & 15, ty = tid >> 4;
  int row0 = blockIdx.y * 64, col0 = blockIdx.x * 64;
  int lm = tid >> 2;              // 0..63 : row within tile for the loader
  int lk = (tid & 3) * 4;         // 0,4,8,12 : k offset for the loader

  float acc[4][4];
#pragma unroll
  for (int i = 0; i < 4; ++i)
#pragma unroll
    for (int j = 0; j < 4; ++j) acc[i][j] = 0.f;

  for (int k0 = 0; k0 < K; k0 += 16) {
    // A tile (guarded rows)
    float4 av = make_float4(0.f, 0.f, 0.f, 0.f);
    int ar = row0 + lm;
    if (ar < M) av = *reinterpret_cast<const float4*>(A + (size_t)ar * K + k0 + lk);
    As[lk + 0][lm] = av.x; As[lk + 1][lm] = av.y;
    As[lk + 2][lm] = av.z; As[lk + 3][lm] = av.w;
    // B tile from Wt[N,K] (transposed into LDS)
    int bn = col0 + lm;             // always < N here
    float4 bv = *reinterpret_cast<const float4*>(Wt + (size_t)bn * K + k0 + lk);
    Bs[lk + 0][lm] = bv.x; Bs[lk + 1][lm] = bv.y;
    Bs[lk + 2][lm] = bv.z; Bs[lk + 3][lm] = bv.w;
    __syncthreads();
#pragma unroll
    for (int kk = 0; kk < 16; ++kk) {
      float4 a = *reinterpret_cast<const float4*>(&As[kk][ty * 4]);
      float4 b = *reinterpret_cast<const float4*>(&Bs[kk][tx * 4]);
      float av4[4] = {a.x, a.y, a.z, a.w};
      float bv4[4] = {b.x, b.y, b.z, b.w};
#pragma unroll
      for (int i = 0; i < 4; ++i)
#pragma unroll
        for (int j = 0; j < 4; ++j) acc[i][j] += av4[i] * bv4[j];
    }
    __syncthreads();
  }
#pragma unroll
  for (int i = 0; i < 4; ++i) {
    int r = row0 + ty * 4 + i;
    if (r < M) {
      float4 o = make_float4(acc[i][0], acc[i][1], acc[i][2], acc[i][3]);
      *reinterpret_cast<float4*>(C + (size_t)r * N + col0 + tx * 4) = o;
    }
  }
}

// ---------------------------------------------------------------------------
// attn: one block per (b_local, w, h).  128 threads.
// Qh  = Qs[b] flat + h*1920  -> [30,64] row-major (contiguous slice)
// Dh  = Y window flat + h*704 -> [11,64] row-major (contiguous slice)
// ctx written at (b_local*100+w)*23040 + h*1920 + q*64 + dh  (contiguous merge)
// ---------------------------------------------------------------------------
__global__ __launch_bounds__(128) void attn_kernel(const float* __restrict__ Qs,
    const float* __restrict__ Y, float* __restrict__ ctx, int b0) {
  int blk = blockIdx.x;
  int h  = blk % NH;
  int w  = (blk / NH) % WNUM;
  int bl = blk / (NH * WNUM);

  __shared__ float Dl[WINSZ * DH_];   // 704
  __shared__ float Ql[LQ * DH_];      // 1920
  __shared__ float Sl[LQ * WINSZ];    // 330

  const float* Yb = Y + ((size_t)(bl * LD + w * WINSZ)) * DIM + h * (WINSZ * DH_);
  const float* Qb = Qs + (size_t)(b0 + bl) * (LQ * DIM) + h * (LQ * DH_);

  int tid = threadIdx.x;
  for (int t = tid; t < WINSZ * DH_; t += 128) Dl[t] = Yb[t];
  for (int t = tid; t < LQ * DH_;  t += 128) Ql[t] = Qb[t];
  __syncthreads();

  int qi = tid >> 2, part = tid & 3;
  if (qi < LQ) {
    for (int k = part; k < WINSZ; k += 4) {
      float dot = 0.f;
#pragma unroll
      for (int d = 0; d < DH_; ++d) dot += Ql[qi * DH_ + d] * Dl[k * DH_ + d];
      Sl[qi * WINSZ + k] = dot;
    }
  }
  __syncthreads();
  if (qi < LQ) {
    float p[WINSZ];
    float mx = -1e30f;
#pragma unroll
    for (int k = 0; k < WINSZ; ++k) { p[k] = Sl[qi * WINSZ + k]; mx = fmaxf(mx, p[k]); }
    float sum = 0.f;
#pragma unroll
    for (int k = 0; k < WINSZ; ++k) { p[k] = expf(p[k] - mx); sum += p[k]; }
    float inv = 1.f / sum;
    float o[16];
#pragma unroll
    for (int j = 0; j < 16; ++j) {
      float a = 0.f;
#pragma unroll
      for (int k = 0; k < WINSZ; ++k) a += p[k] * Dl[k * DH_ + part * 16 + j];
      o[j] = a * inv;
    }
    float* op = ctx + (size_t)(bl * WNUM + w) * (LQ * DIM)
              + h * (LQ * DH_) + qi * DH_ + part * 16;
#pragma unroll
    for (int j = 0; j < 16; j += 4)
      *reinterpret_cast<float4*>(op + j) = make_float4(o[j], o[j+1], o[j+2], o[j+3]);
  }
}

// ---------------------------------------------------------------------------
extern "C" void kernel_launch(void* const* d_in, const int* in_sizes, int n_in,
                              void* d_out, int out_size, void* d_ws, size_t ws_size,
                              hipStream_t stream) {
  const int*   q      = (const int*)d_in[0];
  const int*   dpos   = (const int*)d_in[1];
  const int*   dneg   = (const int*)d_in[2];
  const float* qmask  = (const float*)d_in[3];
  const float* dpmask = (const float*)d_in[4];
  const float* dnmask = (const float*)d_in[5];
  const int*   peflag = (const int*)d_in[6];
  const float* emb    = (const float*)d_in[7];
  const float* Wlin   = (const float*)d_in[8];
  const float* Wout   = (const float*)d_in[9];
  float* out = (float*)d_out;

  float* ws = (float*)d_ws;
  size_t off = 0;
  float* Xq  = ws + off; off += (size_t)B_ * LQ * DIM;        //  368,640
  float* Qsc = ws + off; off += (size_t)B_ * LQ * DIM;        //  368,640
  float* X   = ws + off; off += (size_t)BC * LD * DIM;        // 1,689,600
  float* Y   = ws + off; off += (size_t)BC * LD * DIM;        // 1,689,600
  float* ctx = ws + off; off += (size_t)BC * WNUM * LQ * DIM; // 4,608,000
  // total ~36 MB of d_ws

  // Q path (once)
  prep_q_kernel<<<(B_ * LQ * (DIM/4) + 255) / 256, 256, 0, stream>>>(q, qmask, emb, Xq);
  gemm_bt_f32<<<dim3(DIM / 64, (B_ * LQ + 63) / 64), 256, 0, stream>>>(
      Xq, Wlin, Qsc, B_ * LQ, DIM, DIM);

  const size_t doc_stride = (size_t)B_ * WNUM * LQ * DIM;     // 36,864,000
  for (int doc = 0; doc < 2; ++doc) {
    const int*   didx  = doc ? dneg  : dpos;
    const float* dmask = doc ? dnmask : dpmask;
    float* outd = out + (size_t)doc * doc_stride;

    for (int b0 = 0; b0 < B_; b0 += BC) {
      const int rowsX = BC * LD;          // 2200
      const int rowsC = BC * WNUM * LQ;   // 6000
      prep_d_kernel<<<(rowsX * (DIM/2) + 255) / 256, 256, 0, stream>>>(
          didx, dmask, emb, peflag, X, b0);
      gemm_bt_f32<<<dim3(DIM / 64, (rowsX + 63) / 64), 256, 0, stream>>>(
          X, Wlin, Y, rowsX, DIM, DIM);
      attn_kernel<<<BC * WNUM * NH, 128, 0, stream>>>(Qsc, Y, ctx, b0);
      gemm_bt_f32<<<dim3(DIM / 64, (rowsC + 63) / 64), 256, 0, stream>>>(
          ctx, Wout, outd + (size_t)b0 * WNUM * LQ * DIM, rowsC, DIM, DIM);
    }
  }
}

// Round 2
// 613.522 us; speedup vs baseline: 5.2841x; 5.2841x over previous
//
#include <hip/hip_runtime.h>
#include <hip/hip_bf16.h>
#include <cstdint>
#include <cstddef>

#define B_    16
#define LQ    30
#define LD    1100
#define DIM   768
#define NH    12
#define DH_   64
#define WINSZ 11
#define WNUM  100

typedef __attribute__((ext_vector_type(8))) short short8;
typedef __attribute__((ext_vector_type(4))) float f32x4;

__device__ __forceinline__ void gload_lds16(const void* g, void* l) {
  __builtin_amdgcn_global_load_lds(
      (const __attribute__((address_space(1))) void*)g,
      (__attribute__((address_space(3))) void*)l, 16, 0, 0);
}

// ---------------------------------------------------------------------------
// weights fp32 -> bf16 (once per launch)
// ---------------------------------------------------------------------------
__global__ __launch_bounds__(256) void wconv_kernel(const float* __restrict__ wa,
    const float* __restrict__ wb, __hip_bfloat16* __restrict__ oa,
    __hip_bfloat16* __restrict__ ob) {
  int i = (blockIdx.x * 256 + threadIdx.x) * 4;
  if (i >= DIM * DIM) return;
  float4 va = *reinterpret_cast<const float4*>(wa + i);
  float4 vb = *reinterpret_cast<const float4*>(wb + i);
  union { __hip_bfloat16 h[4]; uint2 u; } pa, pb;
  pa.h[0] = __float2bfloat16(va.x); pa.h[1] = __float2bfloat16(va.y);
  pa.h[2] = __float2bfloat16(va.z); pa.h[3] = __float2bfloat16(va.w);
  pb.h[0] = __float2bfloat16(vb.x); pb.h[1] = __float2bfloat16(vb.y);
  pb.h[2] = __float2bfloat16(vb.z); pb.h[3] = __float2bfloat16(vb.w);
  *reinterpret_cast<uint2*>(oa + i) = pa.u;
  *reinterpret_cast<uint2*>(ob + i) = pb.u;
}

// ---------------------------------------------------------------------------
// prep_q: Xq[row, e] = bf16( emb[q[row], e] * q_mask[row] * 0.125 )
// ---------------------------------------------------------------------------
__global__ __launch_bounds__(256) void prep_q_kernel(const int* __restrict__ q,
    const float* __restrict__ qmask, const float* __restrict__ emb,
    __hip_bfloat16* __restrict__ Xq) {
  int idx = blockIdx.x * 256 + threadIdx.x;        // 480 * 192 quads
  if (idx >= B_ * LQ * (DIM / 4)) return;
  int row = idx / (DIM / 4);
  int c4  = idx % (DIM / 4);
  float m = qmask[row] * 0.125f;
  float4 v = *reinterpret_cast<const float4*>(emb + (size_t)q[row] * DIM + c4 * 4);
  union { __hip_bfloat16 h[4]; uint2 u; } o;
  o.h[0] = __float2bfloat16(v.x * m); o.h[1] = __float2bfloat16(v.y * m);
  o.h[2] = __float2bfloat16(v.z * m); o.h[3] = __float2bfloat16(v.w * m);
  *reinterpret_cast<uint2*>(Xq + (size_t)row * DIM + c4 * 4) = o.u;
}

// ---------------------------------------------------------------------------
// prep_d: X[r,e] = bf16( (emb[tok,e]*sqrt(D) + pe[r%LD, e]) * mask )  (pe if flag)
// 4 elements (2 sin/cos pairs) per thread.
// ---------------------------------------------------------------------------
__global__ __launch_bounds__(256) void prep_d_kernel(const int* __restrict__ didx,
    const float* __restrict__ dmask, const float* __restrict__ emb,
    const int* __restrict__ peflag, __hip_bfloat16* __restrict__ X,
    int b0, int rows) {
  int idx = blockIdx.x * 256 + threadIdx.x;        // rows * 192 quads
  if (idx >= rows * (DIM / 4)) return;
  int r  = idx / (DIM / 4);
  int c4 = idx % (DIM / 4);
  int grow = b0 * LD + r;
  int t = r % LD;
  float m = dmask[grow];
  float4 v = *reinterpret_cast<const float4*>(emb + (size_t)didx[grow] * DIM + c4 * 4);
  if (peflag[0]) {
    int i0 = c4 * 2;                               // pair indices i0, i0+1
    float d0 = expf(-0.023985261387f * (float)i0);
    float d1 = expf(-0.023985261387f * (float)(i0 + 1));
    float s0, c0, s1, c1;
    sincosf((float)t * d0, &s0, &c0);
    sincosf((float)t * d1, &s1, &c1);
    v.x = v.x * 27.712812921102035f + s0;
    v.y = v.y * 27.712812921102035f + c0;
    v.z = v.z * 27.712812921102035f + s1;
    v.w = v.w * 27.712812921102035f + c1;
  }
  union { __hip_bfloat16 h[4]; uint2 u; } o;
  o.h[0] = __float2bfloat16(v.x * m); o.h[1] = __float2bfloat16(v.y * m);
  o.h[2] = __float2bfloat16(v.z * m); o.h[3] = __float2bfloat16(v.w * m);
  *reinterpret_cast<uint2*>(X + (size_t)r * DIM + c4 * 4) = o.u;
}

// ---------------------------------------------------------------------------
// gemm_mfma: C[M,N] = A[M,K](bf16) @ Bt[N,K](bf16)^T, fp32 accum.
// 128x128 tile, BK=32, 256 thr = 4 waves (2x2), 64x64 per wave,
// mfma_f32_16x16x32_bf16, global_load_lds(16B) staging, 2-barrier loop.
// N,K multiples of 128/32. M guarded on store; A over-reads must be mapped.
// ---------------------------------------------------------------------------
template <bool OUT_BF16>
__global__ __launch_bounds__(256) void gemm_mfma(const __hip_bfloat16* __restrict__ A,
    const __hip_bfloat16* __restrict__ Bt, void* __restrict__ Cv,
    int M, int N, int K) {
  __shared__ __hip_bfloat16 As[128 * 32];
  __shared__ __hip_bfloat16 Bs[128 * 32];
  const int tid  = threadIdx.x;
  const int lane = tid & 63;
  const int wave = tid >> 6;
  const int wr = wave >> 1, wc = wave & 1;
  const int row0 = blockIdx.y * 128, col0 = blockIdx.x * 128;
  const int srow = tid >> 2, skoff = (tid & 3) * 8;   // stage: row within 64-row half, k elem offset

  f32x4 acc[4][4] = {};

  for (int k0 = 0; k0 < K; k0 += 32) {
    const __hip_bfloat16* gA0 = A + (size_t)(row0 + srow) * K + k0 + skoff;
    const __hip_bfloat16* gA1 = A + (size_t)(row0 + 64 + srow) * K + k0 + skoff;
    const __hip_bfloat16* gB0 = Bt + (size_t)(col0 + srow) * K + k0 + skoff;
    const __hip_bfloat16* gB1 = Bt + (size_t)(col0 + 64 + srow) * K + k0 + skoff;
    gload_lds16(gA0, As + tid * 8);
    gload_lds16(gA1, As + 2048 + tid * 8);
    gload_lds16(gB0, Bs + tid * 8);
    gload_lds16(gB1, Bs + 2048 + tid * 8);
    __syncthreads();   // drains vmcnt: staged tile visible

    short8 afrag[4], bfrag[4];
#pragma unroll
    for (int m = 0; m < 4; ++m)
      afrag[m] = *reinterpret_cast<const short8*>(
          &As[(size_t)(wr * 64 + m * 16 + (lane & 15)) * 32 + (lane >> 4) * 8]);
#pragma unroll
    for (int n = 0; n < 4; ++n)
      bfrag[n] = *reinterpret_cast<const short8*>(
          &Bs[(size_t)(wc * 64 + n * 16 + (lane & 15)) * 32 + (lane >> 4) * 8]);
#pragma unroll
    for (int m = 0; m < 4; ++m)
#pragma unroll
      for (int n = 0; n < 4; ++n)
        acc[m][n] = __builtin_amdgcn_mfma_f32_16x16x32_bf16(
            afrag[m], bfrag[n], acc[m][n], 0, 0, 0);
    __syncthreads();   // before next-tile overwrite
  }

  // epilogue: C/D layout col=lane&15, row=(lane>>4)*4+j  [m89-verified]
#pragma unroll
  for (int m = 0; m < 4; ++m) {
    int rb = row0 + wr * 64 + m * 16 + (lane >> 4) * 4;
#pragma unroll
    for (int n = 0; n < 4; ++n) {
      int c = col0 + wc * 64 + n * 16 + (lane & 15);
      f32x4 v = acc[m][n];
#pragma unroll
      for (int j = 0; j < 4; ++j) {
        int r = rb + j;
        if (r < M) {
          if constexpr (OUT_BF16)
            ((__hip_bfloat16*)Cv)[(size_t)r * N + c] = __float2bfloat16(v[j]);
          else
            ((float*)Cv)[(size_t)r * N + c] = v[j];
        }
      }
    }
  }
}

// ---------------------------------------------------------------------------
// attn: one block per (b_local, w, h). 128 threads. fp32 math.
// Q slice fp32 [30,64] contiguous; doc head slice bf16 [11,64] contiguous.
// ---------------------------------------------------------------------------
__global__ __launch_bounds__(128) void attn_kernel(const float* __restrict__ Qs,
    const __hip_bfloat16* __restrict__ Y, __hip_bfloat16* __restrict__ ctx, int b0) {
  int blk = blockIdx.x;
  int h  = blk % NH;
  int w  = (blk / NH) % WNUM;
  int bl = blk / (NH * WNUM);

  __shared__ float Dl[WINSZ * DH_];   // 704
  __shared__ float Ql[LQ * DH_];      // 1920
  __shared__ float Sl[LQ * WINSZ];    // 330

  const __hip_bfloat16* Yb = Y + ((size_t)(bl * LD + w * WINSZ)) * DIM + h * (WINSZ * DH_);
  const float* Qb = Qs + (size_t)(b0 + bl) * (LQ * DIM) + h * (LQ * DH_);

  int tid = threadIdx.x;
  for (int t = tid; t < WINSZ * DH_; t += 128) Dl[t] = __bfloat162float(Yb[t]);
  for (int t = tid; t < LQ * DH_;  t += 128) Ql[t] = Qb[t];
  __syncthreads();

  int qi = tid >> 2, part = tid & 3;
  if (qi < LQ) {
    for (int k = part; k < WINSZ; k += 4) {
      float dot = 0.f;
#pragma unroll
      for (int d = 0; d < DH_; ++d) dot += Ql[qi * DH_ + d] * Dl[k * DH_ + d];
      Sl[qi * WINSZ + k] = dot;
    }
  }
  __syncthreads();
  if (qi < LQ) {
    float p[WINSZ];
    float mx = -1e30f;
#pragma unroll
    for (int k = 0; k < WINSZ; ++k) { p[k] = Sl[qi * WINSZ + k]; mx = fmaxf(mx, p[k]); }
    float sum = 0.f;
#pragma unroll
    for (int k = 0; k < WINSZ; ++k) { p[k] = expf(p[k] - mx); sum += p[k]; }
    float inv = 1.f / sum;
    union { __hip_bfloat16 hh[16]; uint4 v[2]; } pk;
#pragma unroll
    for (int j = 0; j < 16; ++j) {
      float a = 0.f;
#pragma unroll
      for (int k = 0; k < WINSZ; ++k) a += p[k] * Dl[k * DH_ + part * 16 + j];
      pk.hh[j] = __float2bfloat16(a * inv);
    }
    __hip_bfloat16* op = ctx + (size_t)(bl * WNUM + w) * (LQ * DIM)
                       + h * (LQ * DH_) + qi * DH_ + part * 16;
    *reinterpret_cast<uint4*>(op)     = pk.v[0];
    *reinterpret_cast<uint4*>(op + 8) = pk.v[1];
  }
}

// ---------------------------------------------------------------------------
extern "C" void kernel_launch(void* const* d_in, const int* in_sizes, int n_in,
                              void* d_out, int out_size, void* d_ws, size_t ws_size,
                              hipStream_t stream) {
  const int*   q      = (const int*)d_in[0];
  const int*   dpos   = (const int*)d_in[1];
  const int*   dneg   = (const int*)d_in[2];
  const float* qmask  = (const float*)d_in[3];
  const float* dpmask = (const float*)d_in[4];
  const float* dnmask = (const float*)d_in[5];
  const int*   peflag = (const int*)d_in[6];
  const float* emb    = (const float*)d_in[7];
  const float* Wlin   = (const float*)d_in[8];
  const float* Wout   = (const float*)d_in[9];
  float* out = (float*)d_out;

  char* ws = (char*)d_ws;
  size_t off = 0;
  auto alloc = [&](size_t bytes) -> char* {
    char* p = ws + off; off += (bytes + 255) & ~(size_t)255; return p;
  };
  __hip_bfloat16* Xq   = (__hip_bfloat16*)alloc((size_t)B_ * LQ * DIM * 2);
  float*          Qsc  = (float*)         alloc((size_t)B_ * LQ * DIM * 4);
  __hip_bfloat16* Wl16 = (__hip_bfloat16*)alloc((size_t)DIM * DIM * 2);
  __hip_bfloat16* Wo16 = (__hip_bfloat16*)alloc((size_t)DIM * DIM * 2);

  // adaptive chunk size: X + Y (bf16, BC*1100*768) + ctx (bf16, BC*3000*768) + slack
  int BC = 16;
  while (BC > 1) {
    size_t need = off + (size_t)BC * LD * DIM * 2 * 2
                + (size_t)BC * WNUM * LQ * DIM * 2 + (1u << 20);
    if (need <= ws_size) break;
    BC >>= 1;
  }
  __hip_bfloat16* X   = (__hip_bfloat16*)alloc((size_t)BC * LD * DIM * 2);
  __hip_bfloat16* Y   = (__hip_bfloat16*)alloc((size_t)BC * LD * DIM * 2);
  __hip_bfloat16* ctx = (__hip_bfloat16*)alloc((size_t)BC * WNUM * LQ * DIM * 2);

  // weights + Q path (once)
  wconv_kernel<<<(DIM * DIM / 4 + 255) / 256, 256, 0, stream>>>(Wlin, Wout, Wl16, Wo16);
  prep_q_kernel<<<(B_ * LQ * (DIM / 4) + 255) / 256, 256, 0, stream>>>(q, qmask, emb, Xq);
  gemm_mfma<false><<<dim3(DIM / 128, (B_ * LQ + 127) / 128), 256, 0, stream>>>(
      Xq, Wl16, Qsc, B_ * LQ, DIM, DIM);

  const size_t doc_stride = (size_t)B_ * WNUM * LQ * DIM;
  for (int doc = 0; doc < 2; ++doc) {
    const int*   didx  = doc ? dneg   : dpos;
    const float* dmask = doc ? dnmask : dpmask;
    float* outd = out + (size_t)doc * doc_stride;

    for (int b0 = 0; b0 < B_; b0 += BC) {
      const int rowsX = BC * LD;          // e.g. 17600 at BC=16
      const int rowsC = BC * WNUM * LQ;   // e.g. 48000 at BC=16
      prep_d_kernel<<<(rowsX * (DIM / 4) + 255) / 256, 256, 0, stream>>>(
          didx, dmask, emb, peflag, X, b0, rowsX);
      gemm_mfma<true><<<dim3(DIM / 128, (rowsX + 127) / 128), 256, 0, stream>>>(
          X, Wl16, Y, rowsX, DIM, DIM);
      attn_kernel<<<BC * WNUM * NH, 128, 0, stream>>>(Qsc, Y, ctx, b0);
      gemm_mfma<false><<<dim3(DIM / 128, (rowsC + 127) / 128), 256, 0, stream>>>(
          ctx, Wo16, outd + (size_t)b0 * WNUM * LQ * DIM, rowsC, DIM, DIM);
    }
  }
}

// Round 3
// 489.727 us; speedup vs baseline: 6.6199x; 1.2528x over previous
//
#include <hip/hip_runtime.h>
#include <hip/hip_bf16.h>
#include <cstdint>
#include <cstddef>

#define B_    16
#define LQ    30
#define LD    1100
#define DIM   768
#define NH    12
#define DH_   64
#define WINSZ 11
#define WNUM  100

typedef __attribute__((ext_vector_type(8))) short short8;
typedef __attribute__((ext_vector_type(4))) float f32x4;

__device__ __forceinline__ void gload_lds16(const void* g, void* l) {
  __builtin_amdgcn_global_load_lds(
      (const __attribute__((address_space(1))) void*)g,
      (__attribute__((address_space(3))) void*)l, 16, 0, 0);
}

// ---------------------------------------------------------------------------
// weights fp32 -> bf16 (once per launch)
// ---------------------------------------------------------------------------
__global__ __launch_bounds__(256) void wconv_kernel(const float* __restrict__ wa,
    const float* __restrict__ wb, __hip_bfloat16* __restrict__ oa,
    __hip_bfloat16* __restrict__ ob) {
  int i = (blockIdx.x * 256 + threadIdx.x) * 4;
  if (i >= DIM * DIM) return;
  float4 va = *reinterpret_cast<const float4*>(wa + i);
  float4 vb = *reinterpret_cast<const float4*>(wb + i);
  union { __hip_bfloat16 h[4]; uint2 u; } pa, pb;
  pa.h[0] = __float2bfloat16(va.x); pa.h[1] = __float2bfloat16(va.y);
  pa.h[2] = __float2bfloat16(va.z); pa.h[3] = __float2bfloat16(va.w);
  pb.h[0] = __float2bfloat16(vb.x); pb.h[1] = __float2bfloat16(vb.y);
  pb.h[2] = __float2bfloat16(vb.z); pb.h[3] = __float2bfloat16(vb.w);
  *reinterpret_cast<uint2*>(oa + i) = pa.u;
  *reinterpret_cast<uint2*>(ob + i) = pb.u;
}

// ---------------------------------------------------------------------------
// prep_q: Xq[row, e] = bf16( emb[q[row], e] * q_mask[row] * 0.125 )
// ---------------------------------------------------------------------------
__global__ __launch_bounds__(256) void prep_q_kernel(const int* __restrict__ q,
    const float* __restrict__ qmask, const float* __restrict__ emb,
    __hip_bfloat16* __restrict__ Xq) {
  int idx = blockIdx.x * 256 + threadIdx.x;        // 480 * 192 quads
  if (idx >= B_ * LQ * (DIM / 4)) return;
  int row = idx / (DIM / 4);
  int c4  = idx % (DIM / 4);
  float m = qmask[row] * 0.125f;
  float4 v = *reinterpret_cast<const float4*>(emb + (size_t)q[row] * DIM + c4 * 4);
  union { __hip_bfloat16 h[4]; uint2 u; } o;
  o.h[0] = __float2bfloat16(v.x * m); o.h[1] = __float2bfloat16(v.y * m);
  o.h[2] = __float2bfloat16(v.z * m); o.h[3] = __float2bfloat16(v.w * m);
  *reinterpret_cast<uint2*>(Xq + (size_t)row * DIM + c4 * 4) = o.u;
}

// ---------------------------------------------------------------------------
// prep_d: X[r,e] = bf16( (emb[tok,e]*sqrt(D) + pe[r%LD, e]) * mask )  (pe if flag)
// ---------------------------------------------------------------------------
__global__ __launch_bounds__(256) void prep_d_kernel(const int* __restrict__ didx,
    const float* __restrict__ dmask, const float* __restrict__ emb,
    const int* __restrict__ peflag, __hip_bfloat16* __restrict__ X,
    int b0, int rows) {
  int idx = blockIdx.x * 256 + threadIdx.x;        // rows * 192 quads
  if (idx >= rows * (DIM / 4)) return;
  int r  = idx / (DIM / 4);
  int c4 = idx % (DIM / 4);
  int grow = b0 * LD + r;
  int t = r % LD;
  float m = dmask[grow];
  float4 v = *reinterpret_cast<const float4*>(emb + (size_t)didx[grow] * DIM + c4 * 4);
  if (peflag[0]) {
    int i0 = c4 * 2;                               // pair indices i0, i0+1
    float d0 = expf(-0.023985261387f * (float)i0);
    float d1 = expf(-0.023985261387f * (float)(i0 + 1));
    float s0, c0, s1, c1;
    sincosf((float)t * d0, &s0, &c0);
    sincosf((float)t * d1, &s1, &c1);
    v.x = v.x * 27.712812921102035f + s0;
    v.y = v.y * 27.712812921102035f + c0;
    v.z = v.z * 27.712812921102035f + s1;
    v.w = v.w * 27.712812921102035f + c1;
  }
  union { __hip_bfloat16 h[4]; uint2 u; } o;
  o.h[0] = __float2bfloat16(v.x * m); o.h[1] = __float2bfloat16(v.y * m);
  o.h[2] = __float2bfloat16(v.z * m); o.h[3] = __float2bfloat16(v.w * m);
  *reinterpret_cast<uint2*>(X + (size_t)r * DIM + c4 * 4) = o.u;
}

// ---------------------------------------------------------------------------
// gemm_mfma: C[M,N] = A[M,K](bf16) @ Bt[N,K](bf16)^T, fp32 accum.
// 128x128 tile, BK=32, 256 thr = 4 waves (2x2), mfma_f32_16x16x32_bf16,
// global_load_lds(16B) staging, 2-barrier loop.  (m97 structure, verified R2)
// ---------------------------------------------------------------------------
template <bool OUT_BF16>
__global__ __launch_bounds__(256) void gemm_mfma(const __hip_bfloat16* __restrict__ A,
    const __hip_bfloat16* __restrict__ Bt, void* __restrict__ Cv,
    int M, int N, int K) {
  __shared__ __hip_bfloat16 As[128 * 32];
  __shared__ __hip_bfloat16 Bs[128 * 32];
  const int tid  = threadIdx.x;
  const int lane = tid & 63;
  const int wave = tid >> 6;
  const int wr = wave >> 1, wc = wave & 1;
  const int row0 = blockIdx.y * 128, col0 = blockIdx.x * 128;
  const int srow = tid >> 2, skoff = (tid & 3) * 8;

  f32x4 acc[4][4] = {};

  for (int k0 = 0; k0 < K; k0 += 32) {
    const __hip_bfloat16* gA0 = A + (size_t)(row0 + srow) * K + k0 + skoff;
    const __hip_bfloat16* gA1 = A + (size_t)(row0 + 64 + srow) * K + k0 + skoff;
    const __hip_bfloat16* gB0 = Bt + (size_t)(col0 + srow) * K + k0 + skoff;
    const __hip_bfloat16* gB1 = Bt + (size_t)(col0 + 64 + srow) * K + k0 + skoff;
    gload_lds16(gA0, As + tid * 8);
    gload_lds16(gA1, As + 2048 + tid * 8);
    gload_lds16(gB0, Bs + tid * 8);
    gload_lds16(gB1, Bs + 2048 + tid * 8);
    __syncthreads();

    short8 afrag[4], bfrag[4];
#pragma unroll
    for (int m = 0; m < 4; ++m)
      afrag[m] = *reinterpret_cast<const short8*>(
          &As[(size_t)(wr * 64 + m * 16 + (lane & 15)) * 32 + (lane >> 4) * 8]);
#pragma unroll
    for (int n = 0; n < 4; ++n)
      bfrag[n] = *reinterpret_cast<const short8*>(
          &Bs[(size_t)(wc * 64 + n * 16 + (lane & 15)) * 32 + (lane >> 4) * 8]);
#pragma unroll
    for (int m = 0; m < 4; ++m)
#pragma unroll
      for (int n = 0; n < 4; ++n)
        acc[m][n] = __builtin_amdgcn_mfma_f32_16x16x32_bf16(
            afrag[m], bfrag[n], acc[m][n], 0, 0, 0);
    __syncthreads();
  }

#pragma unroll
  for (int m = 0; m < 4; ++m) {
    int rb = row0 + wr * 64 + m * 16 + (lane >> 4) * 4;
#pragma unroll
    for (int n = 0; n < 4; ++n) {
      int c = col0 + wc * 64 + n * 16 + (lane & 15);
      f32x4 v = acc[m][n];
#pragma unroll
      for (int j = 0; j < 4; ++j) {
        int r = rb + j;
        if (r < M) {
          if constexpr (OUT_BF16)
            ((__hip_bfloat16*)Cv)[(size_t)r * N + c] = __float2bfloat16(v[j]);
          else
            ((float*)Cv)[(size_t)r * N + c] = v[j];
        }
      }
    }
  }
}

// ---------------------------------------------------------------------------
// attn v2: one block per (b_local, w, h), 120 threads = 30 qi x 4 part.
// Q segment (16 floats) in REGISTERS straight from global (coalesced, L2-hot).
// Only D staged in LDS (11x64 fp32, broadcast/conflict-free float4 reads).
// QK^T: per-lane 16-col partial dots + 2x shfl_xor within the 4-lane group.
// Softmax fully in-lane. PV: per-lane 16-col output.
// ---------------------------------------------------------------------------
__global__ __launch_bounds__(128) void attn_kernel(const float* __restrict__ Qs,
    const __hip_bfloat16* __restrict__ Y, __hip_bfloat16* __restrict__ ctx, int b0) {
  int blk = blockIdx.x;
  int h  = blk % NH;
  int w  = (blk / NH) % WNUM;
  int bl = blk / (NH * WNUM);

  __shared__ float Dl[WINSZ][DH_];    // 2816 B

  const __hip_bfloat16* Yb = Y + ((size_t)(bl * LD + w * WINSZ)) * DIM + h * (WINSZ * DH_);
  const float* Qb = Qs + (size_t)(b0 + bl) * (LQ * DIM) + h * (LQ * DH_);

  int tid = threadIdx.x;
  int qi = tid >> 2, part = tid & 3;

  // stage D: 704 bf16, 88 threads x 8 elems, coalesced
  if (tid < 88) {
    uint4 raw = *reinterpret_cast<const uint4*>(Yb + tid * 8);
    const __hip_bfloat16* hp = reinterpret_cast<const __hip_bfloat16*>(&raw);
    float* dst = &Dl[0][0] + tid * 8;
#pragma unroll
    for (int j = 0; j < 8; ++j) dst[j] = __bfloat162float(hp[j]);
  }

  // Q segment -> regs (fully coalesced across the block per j)
  float4 qreg[4];
#pragma unroll
  for (int j = 0; j < 4; ++j)
    qreg[j] = *reinterpret_cast<const float4*>(Qb + qi * DH_ + part * 16 + j * 4);
  __syncthreads();

  // partial dots over this lane's 16-col segment
  float dot[WINSZ];
#pragma unroll
  for (int k = 0; k < WINSZ; ++k) {
    const float4* dp = reinterpret_cast<const float4*>(&Dl[k][part * 16]);
    float s = 0.f;
#pragma unroll
    for (int j = 0; j < 4; ++j) {
      float4 dv = dp[j];
      s += qreg[j].x * dv.x + qreg[j].y * dv.y + qreg[j].z * dv.z + qreg[j].w * dv.w;
    }
    dot[k] = s;
  }
  // sum the 4 partials within each 4-lane group
#pragma unroll
  for (int k = 0; k < WINSZ; ++k) {
    dot[k] += __shfl_xor(dot[k], 1);
    dot[k] += __shfl_xor(dot[k], 2);
  }
  // in-lane softmax (redundant x4 per qi, trivial)
  float mx = -1e30f;
#pragma unroll
  for (int k = 0; k < WINSZ; ++k) mx = fmaxf(mx, dot[k]);
  float sum = 0.f;
#pragma unroll
  for (int k = 0; k < WINSZ; ++k) { dot[k] = expf(dot[k] - mx); sum += dot[k]; }
  float inv = 1.f / sum;

  // PV over this lane's 16-col segment
  float4 o[4] = {};
#pragma unroll
  for (int k = 0; k < WINSZ; ++k) {
    float pk = dot[k];
    const float4* dp = reinterpret_cast<const float4*>(&Dl[k][part * 16]);
#pragma unroll
    for (int j = 0; j < 4; ++j) {
      float4 dv = dp[j];
      o[j].x += pk * dv.x; o[j].y += pk * dv.y;
      o[j].z += pk * dv.z; o[j].w += pk * dv.w;
    }
  }
  union { __hip_bfloat16 hh[16]; uint4 v[2]; } pk;
#pragma unroll
  for (int j = 0; j < 4; ++j) {
    pk.hh[j * 4 + 0] = __float2bfloat16(o[j].x * inv);
    pk.hh[j * 4 + 1] = __float2bfloat16(o[j].y * inv);
    pk.hh[j * 4 + 2] = __float2bfloat16(o[j].z * inv);
    pk.hh[j * 4 + 3] = __float2bfloat16(o[j].w * inv);
  }
  __hip_bfloat16* op = ctx + (size_t)(bl * WNUM + w) * (LQ * DIM)
                     + h * (LQ * DH_) + qi * DH_ + part * 16;
  *reinterpret_cast<uint4*>(op)     = pk.v[0];
  *reinterpret_cast<uint4*>(op + 8) = pk.v[1];
}

// ---------------------------------------------------------------------------
extern "C" void kernel_launch(void* const* d_in, const int* in_sizes, int n_in,
                              void* d_out, int out_size, void* d_ws, size_t ws_size,
                              hipStream_t stream) {
  const int*   q      = (const int*)d_in[0];
  const int*   dpos   = (const int*)d_in[1];
  const int*   dneg   = (const int*)d_in[2];
  const float* qmask  = (const float*)d_in[3];
  const float* dpmask = (const float*)d_in[4];
  const float* dnmask = (const float*)d_in[5];
  const int*   peflag = (const int*)d_in[6];
  const float* emb    = (const float*)d_in[7];
  const float* Wlin   = (const float*)d_in[8];
  const float* Wout   = (const float*)d_in[9];
  float* out = (float*)d_out;

  char* ws = (char*)d_ws;
  size_t off = 0;
  auto alloc = [&](size_t bytes) -> char* {
    char* p = ws + off; off += (bytes + 255) & ~(size_t)255; return p;
  };
  __hip_bfloat16* Xq   = (__hip_bfloat16*)alloc((size_t)B_ * LQ * DIM * 2);
  float*          Qsc  = (float*)         alloc((size_t)B_ * LQ * DIM * 4);
  __hip_bfloat16* Wl16 = (__hip_bfloat16*)alloc((size_t)DIM * DIM * 2);
  __hip_bfloat16* Wo16 = (__hip_bfloat16*)alloc((size_t)DIM * DIM * 2);

  int BC = 16;
  while (BC > 1) {
    size_t need = off + (size_t)BC * LD * DIM * 2 * 2
                + (size_t)BC * WNUM * LQ * DIM * 2 + (1u << 20);
    if (need <= ws_size) break;
    BC >>= 1;
  }
  __hip_bfloat16* X   = (__hip_bfloat16*)alloc((size_t)BC * LD * DIM * 2);
  __hip_bfloat16* Y   = (__hip_bfloat16*)alloc((size_t)BC * LD * DIM * 2);
  __hip_bfloat16* ctx = (__hip_bfloat16*)alloc((size_t)BC * WNUM * LQ * DIM * 2);

  wconv_kernel<<<(DIM * DIM / 4 + 255) / 256, 256, 0, stream>>>(Wlin, Wout, Wl16, Wo16);
  prep_q_kernel<<<(B_ * LQ * (DIM / 4) + 255) / 256, 256, 0, stream>>>(q, qmask, emb, Xq);
  gemm_mfma<false><<<dim3(DIM / 128, (B_ * LQ + 127) / 128), 256, 0, stream>>>(
      Xq, Wl16, Qsc, B_ * LQ, DIM, DIM);

  const size_t doc_stride = (size_t)B_ * WNUM * LQ * DIM;
  for (int doc = 0; doc < 2; ++doc) {
    const int*   didx  = doc ? dneg   : dpos;
    const float* dmask = doc ? dnmask : dpmask;
    float* outd = out + (size_t)doc * doc_stride;

    for (int b0 = 0; b0 < B_; b0 += BC) {
      const int rowsX = BC * LD;
      const int rowsC = BC * WNUM * LQ;
      prep_d_kernel<<<(rowsX * (DIM / 4) + 255) / 256, 256, 0, stream>>>(
          didx, dmask, emb, peflag, X, b0, rowsX);
      gemm_mfma<true><<<dim3(DIM / 128, (rowsX + 127) / 128), 256, 0, stream>>>(
          X, Wl16, Y, rowsX, DIM, DIM);
      attn_kernel<<<BC * WNUM * NH, 120, 0, stream>>>(Qsc, Y, ctx, b0);
      gemm_mfma<false><<<dim3(DIM / 128, (rowsC + 127) / 128), 256, 0, stream>>>(
          ctx, Wo16, outd + (size_t)b0 * WNUM * LQ * DIM, rowsC, DIM, DIM);
    }
  }
}

// Round 4
// 456.434 us; speedup vs baseline: 7.1027x; 1.0729x over previous
//
#include <hip/hip_runtime.h>
#include <hip/hip_bf16.h>
#include <cstdint>
#include <cstddef>

#define B_    16
#define LQ    30
#define LD    1100
#define DIM   768
#define NH    12
#define DH_   64
#define WINSZ 11
#define WNUM  100
#define NSLOT 32              // 2 docs x 16 batches

typedef __attribute__((ext_vector_type(8))) short short8;
typedef __attribute__((ext_vector_type(4))) float f32x4;

__device__ __forceinline__ void gload_lds16(const void* g, void* l) {
  __builtin_amdgcn_global_load_lds(
      (const __attribute__((address_space(1))) void*)g,
      (__attribute__((address_space(3))) void*)l, 16, 0, 0);
}

// ---------------------------------------------------------------------------
// weights fp32 -> bf16 (once per launch)
// ---------------------------------------------------------------------------
__global__ __launch_bounds__(256) void wconv_kernel(const float* __restrict__ wa,
    const float* __restrict__ wb, __hip_bfloat16* __restrict__ oa,
    __hip_bfloat16* __restrict__ ob) {
  int i = (blockIdx.x * 256 + threadIdx.x) * 4;
  if (i >= DIM * DIM) return;
  float4 va = *reinterpret_cast<const float4*>(wa + i);
  float4 vb = *reinterpret_cast<const float4*>(wb + i);
  union { __hip_bfloat16 h[4]; uint2 u; } pa, pb;
  pa.h[0] = __float2bfloat16(va.x); pa.h[1] = __float2bfloat16(va.y);
  pa.h[2] = __float2bfloat16(va.z); pa.h[3] = __float2bfloat16(va.w);
  pb.h[0] = __float2bfloat16(vb.x); pb.h[1] = __float2bfloat16(vb.y);
  pb.h[2] = __float2bfloat16(vb.z); pb.h[3] = __float2bfloat16(vb.w);
  *reinterpret_cast<uint2*>(oa + i) = pa.u;
  *reinterpret_cast<uint2*>(ob + i) = pb.u;
}

// ---------------------------------------------------------------------------
// prep_q: Xq[row, e] = bf16( emb[q[row], e] * q_mask[row] * 0.125 )
// ---------------------------------------------------------------------------
__global__ __launch_bounds__(256) void prep_q_kernel(const int* __restrict__ q,
    const float* __restrict__ qmask, const float* __restrict__ emb,
    __hip_bfloat16* __restrict__ Xq) {
  int idx = blockIdx.x * 256 + threadIdx.x;        // 480 * 192 quads
  if (idx >= B_ * LQ * (DIM / 4)) return;
  int row = idx / (DIM / 4);
  int c4  = idx % (DIM / 4);
  float m = qmask[row] * 0.125f;
  float4 v = *reinterpret_cast<const float4*>(emb + (size_t)q[row] * DIM + c4 * 4);
  union { __hip_bfloat16 h[4]; uint2 u; } o;
  o.h[0] = __float2bfloat16(v.x * m); o.h[1] = __float2bfloat16(v.y * m);
  o.h[2] = __float2bfloat16(v.z * m); o.h[3] = __float2bfloat16(v.w * m);
  *reinterpret_cast<uint2*>(Xq + (size_t)row * DIM + c4 * 4) = o.u;
}

// ---------------------------------------------------------------------------
// prep_d (both docs): slot s = s0 + r/LD, doc = s>>4, b = s&15, t = r%LD.
// X[r,e] = bf16( (emb[tok,e]*sqrt(D) + pe[t,e]) * mask )   (pe if flag)
// ---------------------------------------------------------------------------
__global__ __launch_bounds__(256) void prep_d_kernel(const int* __restrict__ dpos,
    const int* __restrict__ dneg, const float* __restrict__ dpmask,
    const float* __restrict__ dnmask, const float* __restrict__ emb,
    const int* __restrict__ peflag, __hip_bfloat16* __restrict__ X,
    int s0, int rows) {
  int idx = blockIdx.x * 256 + threadIdx.x;        // rows * 192 quads
  if (idx >= rows * (DIM / 4)) return;
  int r  = idx / (DIM / 4);
  int c4 = idx % (DIM / 4);
  int s = s0 + r / LD;
  int t = r % LD;
  int doc = s >> 4, b = s & 15;
  const int*   di = doc ? dneg   : dpos;
  const float* dm = doc ? dnmask : dpmask;
  int grow = b * LD + t;
  float m = dm[grow];
  float4 v = *reinterpret_cast<const float4*>(emb + (size_t)di[grow] * DIM + c4 * 4);
  if (peflag[0]) {
    int i0 = c4 * 2;                               // pair indices i0, i0+1
    float d0 = expf(-0.023985261387f * (float)i0);
    float d1 = expf(-0.023985261387f * (float)(i0 + 1));
    float s0f, c0f, s1f, c1f;
    sincosf((float)t * d0, &s0f, &c0f);
    sincosf((float)t * d1, &s1f, &c1f);
    v.x = v.x * 27.712812921102035f + s0f;
    v.y = v.y * 27.712812921102035f + c0f;
    v.z = v.z * 27.712812921102035f + s1f;
    v.w = v.w * 27.712812921102035f + c1f;
  }
  union { __hip_bfloat16 h[4]; uint2 u; } o;
  o.h[0] = __float2bfloat16(v.x * m); o.h[1] = __float2bfloat16(v.y * m);
  o.h[2] = __float2bfloat16(v.z * m); o.h[3] = __float2bfloat16(v.w * m);
  *reinterpret_cast<uint2*>(X + (size_t)r * DIM + c4 * 4) = o.u;
}

// ---------------------------------------------------------------------------
// gemm_mfma: C[M,N] = A[M,K](bf16) @ Bt[N,K](bf16)^T, fp32 accum.
// 128x128 tile, BK=32, 256 thr = 4 waves (2x2), mfma_f32_16x16x32_bf16,
// global_load_lds(16B) staging, 2-barrier loop  (verified R2/R3 structure).
// 1D grid with bijective XCD swizzle (m204): panel-sharing blocks (same ty,
// consecutive tx since tx is fastest) land on the same XCD for L2/L3 reuse.
// A must be readable up to tile-padded rows (allocate M rounded up to 128).
// ---------------------------------------------------------------------------
template <bool OUT_BF16>
__global__ __launch_bounds__(256) void gemm_mfma(const __hip_bfloat16* __restrict__ A,
    const __hip_bfloat16* __restrict__ Bt, void* __restrict__ Cv,
    int M, int N, int K, int tilesX) {
  __shared__ __hip_bfloat16 As[128 * 32];
  __shared__ __hip_bfloat16 Bs[128 * 32];
  const int nwg  = gridDim.x;
  const int orig = blockIdx.x;
  const int q8 = nwg >> 3, r8 = nwg & 7;
  const int xcd = orig & 7, pos = orig >> 3;
  const int wgid = (xcd < r8 ? xcd * (q8 + 1) : r8 * (q8 + 1) + (xcd - r8) * q8) + pos;
  const int row0 = (wgid / tilesX) * 128;
  const int col0 = (wgid % tilesX) * 128;

  const int tid  = threadIdx.x;
  const int lane = tid & 63;
  const int wave = tid >> 6;
  const int wr = wave >> 1, wc = wave & 1;
  const int srow = tid >> 2, skoff = (tid & 3) * 8;

  f32x4 acc[4][4] = {};

  for (int k0 = 0; k0 < K; k0 += 32) {
    const __hip_bfloat16* gA0 = A + (size_t)(row0 + srow) * K + k0 + skoff;
    const __hip_bfloat16* gA1 = A + (size_t)(row0 + 64 + srow) * K + k0 + skoff;
    const __hip_bfloat16* gB0 = Bt + (size_t)(col0 + srow) * K + k0 + skoff;
    const __hip_bfloat16* gB1 = Bt + (size_t)(col0 + 64 + srow) * K + k0 + skoff;
    gload_lds16(gA0, As + tid * 8);
    gload_lds16(gA1, As + 2048 + tid * 8);
    gload_lds16(gB0, Bs + tid * 8);
    gload_lds16(gB1, Bs + 2048 + tid * 8);
    __syncthreads();

    short8 afrag[4], bfrag[4];
#pragma unroll
    for (int m = 0; m < 4; ++m)
      afrag[m] = *reinterpret_cast<const short8*>(
          &As[(size_t)(wr * 64 + m * 16 + (lane & 15)) * 32 + (lane >> 4) * 8]);
#pragma unroll
    for (int n = 0; n < 4; ++n)
      bfrag[n] = *reinterpret_cast<const short8*>(
          &Bs[(size_t)(wc * 64 + n * 16 + (lane & 15)) * 32 + (lane >> 4) * 8]);
#pragma unroll
    for (int m = 0; m < 4; ++m)
#pragma unroll
      for (int n = 0; n < 4; ++n)
        acc[m][n] = __builtin_amdgcn_mfma_f32_16x16x32_bf16(
            afrag[m], bfrag[n], acc[m][n], 0, 0, 0);
    __syncthreads();
  }

#pragma unroll
  for (int m = 0; m < 4; ++m) {
    int rb = row0 + wr * 64 + m * 16 + (lane >> 4) * 4;
#pragma unroll
    for (int n = 0; n < 4; ++n) {
      int c = col0 + wc * 64 + n * 16 + (lane & 15);
      f32x4 v = acc[m][n];
#pragma unroll
      for (int j = 0; j < 4; ++j) {
        int r = rb + j;
        if (r < M) {
          if constexpr (OUT_BF16)
            ((__hip_bfloat16*)Cv)[(size_t)r * N + c] = __float2bfloat16(v[j]);
          else
            ((float*)Cv)[(size_t)r * N + c] = v[j];
        }
      }
    }
  }
}

// ---------------------------------------------------------------------------
// attn: one block per (slot_local, w, h), 120 threads = 30 qi x 4 part.
// Q segment in registers from global (L2-hot); D staged in LDS fp32
// (broadcast float4 reads, conflict-free); shfl_xor partial-dot reduce.
// ---------------------------------------------------------------------------
__global__ __launch_bounds__(128) void attn_kernel(const float* __restrict__ Qs,
    const __hip_bfloat16* __restrict__ Y, __hip_bfloat16* __restrict__ ctx, int s0) {
  int blk = blockIdx.x;
  int h  = blk % NH;
  int w  = (blk / NH) % WNUM;
  int sl = blk / (NH * WNUM);
  int b  = (s0 + sl) & 15;          // batch index (doc-independent Q)

  __shared__ float Dl[WINSZ][DH_];

  const __hip_bfloat16* Yb = Y + ((size_t)(sl * LD + w * WINSZ)) * DIM + h * (WINSZ * DH_);
  const float* Qb = Qs + (size_t)b * (LQ * DIM) + h * (LQ * DH_);

  int tid = threadIdx.x;
  int qi = tid >> 2, part = tid & 3;

  if (tid < 88) {
    uint4 raw = *reinterpret_cast<const uint4*>(Yb + tid * 8);
    const __hip_bfloat16* hp = reinterpret_cast<const __hip_bfloat16*>(&raw);
    float* dst = &Dl[0][0] + tid * 8;
#pragma unroll
    for (int j = 0; j < 8; ++j) dst[j] = __bfloat162float(hp[j]);
  }

  float4 qreg[4];
#pragma unroll
  for (int j = 0; j < 4; ++j)
    qreg[j] = *reinterpret_cast<const float4*>(Qb + qi * DH_ + part * 16 + j * 4);
  __syncthreads();

  float dot[WINSZ];
#pragma unroll
  for (int k = 0; k < WINSZ; ++k) {
    const float4* dp = reinterpret_cast<const float4*>(&Dl[k][part * 16]);
    float s = 0.f;
#pragma unroll
    for (int j = 0; j < 4; ++j) {
      float4 dv = dp[j];
      s += qreg[j].x * dv.x + qreg[j].y * dv.y + qreg[j].z * dv.z + qreg[j].w * dv.w;
    }
    dot[k] = s;
  }
#pragma unroll
  for (int k = 0; k < WINSZ; ++k) {
    dot[k] += __shfl_xor(dot[k], 1);
    dot[k] += __shfl_xor(dot[k], 2);
  }
  float mx = -1e30f;
#pragma unroll
  for (int k = 0; k < WINSZ; ++k) mx = fmaxf(mx, dot[k]);
  float sum = 0.f;
#pragma unroll
  for (int k = 0; k < WINSZ; ++k) { dot[k] = expf(dot[k] - mx); sum += dot[k]; }
  float inv = 1.f / sum;

  float4 o[4] = {};
#pragma unroll
  for (int k = 0; k < WINSZ; ++k) {
    float pk = dot[k];
    const float4* dp = reinterpret_cast<const float4*>(&Dl[k][part * 16]);
#pragma unroll
    for (int j = 0; j < 4; ++j) {
      float4 dv = dp[j];
      o[j].x += pk * dv.x; o[j].y += pk * dv.y;
      o[j].z += pk * dv.z; o[j].w += pk * dv.w;
    }
  }
  union { __hip_bfloat16 hh[16]; uint4 v[2]; } pk;
#pragma unroll
  for (int j = 0; j < 4; ++j) {
    pk.hh[j * 4 + 0] = __float2bfloat16(o[j].x * inv);
    pk.hh[j * 4 + 1] = __float2bfloat16(o[j].y * inv);
    pk.hh[j * 4 + 2] = __float2bfloat16(o[j].z * inv);
    pk.hh[j * 4 + 3] = __float2bfloat16(o[j].w * inv);
  }
  __hip_bfloat16* op = ctx + (size_t)(sl * WNUM + w) * (LQ * DIM)
                     + h * (LQ * DH_) + qi * DH_ + part * 16;
  *reinterpret_cast<uint4*>(op)     = pk.v[0];
  *reinterpret_cast<uint4*>(op + 8) = pk.v[1];
}

// ---------------------------------------------------------------------------
extern "C" void kernel_launch(void* const* d_in, const int* in_sizes, int n_in,
                              void* d_out, int out_size, void* d_ws, size_t ws_size,
                              hipStream_t stream) {
  const int*   q      = (const int*)d_in[0];
  const int*   dpos   = (const int*)d_in[1];
  const int*   dneg   = (const int*)d_in[2];
  const float* qmask  = (const float*)d_in[3];
  const float* dpmask = (const float*)d_in[4];
  const float* dnmask = (const float*)d_in[5];
  const int*   peflag = (const int*)d_in[6];
  const float* emb    = (const float*)d_in[7];
  const float* Wlin   = (const float*)d_in[8];
  const float* Wout   = (const float*)d_in[9];
  float* out = (float*)d_out;

  char* ws = (char*)d_ws;
  size_t off = 0;
  auto alloc = [&](size_t bytes) -> char* {
    char* p = ws + off; off += (bytes + 255) & ~(size_t)255; return p;
  };
  __hip_bfloat16* Xq   = (__hip_bfloat16*)alloc((size_t)B_ * LQ * DIM * 2);
  float*          Qsc  = (float*)         alloc((size_t)B_ * LQ * DIM * 4);
  __hip_bfloat16* Wl16 = (__hip_bfloat16*)alloc((size_t)DIM * DIM * 2);
  __hip_bfloat16* Wo16 = (__hip_bfloat16*)alloc((size_t)DIM * DIM * 2);

  // slots per chunk: all 32 (both docs) if ws allows; else halve.
  // buffers tile-padded (+128 rows) so gemm A-overreads stay in-bounds.
  int SC = NSLOT;
  while (SC > 1) {
    size_t need = off
        + ((size_t)SC * LD + 128) * DIM * 2 * 2                 // X + Y
        + ((size_t)SC * WNUM * LQ + 128) * DIM * 2 + (1u << 20);// ctx
    if (need <= ws_size) break;
    SC >>= 1;
  }
  __hip_bfloat16* X   = (__hip_bfloat16*)alloc(((size_t)SC * LD + 128) * DIM * 2);
  __hip_bfloat16* Y   = (__hip_bfloat16*)alloc(((size_t)SC * LD + 128) * DIM * 2);
  __hip_bfloat16* ctx = (__hip_bfloat16*)alloc(((size_t)SC * WNUM * LQ + 128) * DIM * 2);

  wconv_kernel<<<(DIM * DIM / 4 + 255) / 256, 256, 0, stream>>>(Wlin, Wout, Wl16, Wo16);
  prep_q_kernel<<<(B_ * LQ * (DIM / 4) + 255) / 256, 256, 0, stream>>>(q, qmask, emb, Xq);
  {
    int tilesX = DIM / 128, tilesY = (B_ * LQ + 127) / 128;   // Xq padded? M=480 < 512
    // Xq is only 480 rows; pad via Qsc region is not guaranteed — give Xq its own pad:
    // (Xq alloc rounds to 256B; overread of 32 rows x 1536B = 48KB stays inside ws
    //  because Qsc/W buffers follow immediately.)
    gemm_mfma<false><<<tilesX * tilesY, 256, 0, stream>>>(
        Xq, Wl16, Qsc, B_ * LQ, DIM, DIM, tilesX);
  }

  for (int s0 = 0; s0 < NSLOT; s0 += SC) {
    const int rowsX = SC * LD;           // 35200 at SC=32
    const int rowsC = SC * WNUM * LQ;    // 96000 at SC=32
    prep_d_kernel<<<(rowsX * (DIM / 4) + 255) / 256, 256, 0, stream>>>(
        dpos, dneg, dpmask, dnmask, emb, peflag, X, s0, rowsX);
    {
      int tilesX = DIM / 128, tilesY = (rowsX + 127) / 128;
      gemm_mfma<true><<<tilesX * tilesY, 256, 0, stream>>>(
          X, Wl16, Y, rowsX, DIM, DIM, tilesX);
    }
    attn_kernel<<<SC * WNUM * NH, 120, 0, stream>>>(Qsc, Y, ctx, s0);
    {
      int tilesX = DIM / 128, tilesY = (rowsC + 127) / 128;
      gemm_mfma<false><<<tilesX * tilesY, 256, 0, stream>>>(
          ctx, Wo16, out + (size_t)s0 * WNUM * LQ * DIM, rowsC, DIM, DIM, tilesX);
    }
  }
}

// Round 5
// 444.109 us; speedup vs baseline: 7.2998x; 1.0278x over previous
//
#include <hip/hip_runtime.h>
#include <hip/hip_bf16.h>
#include <cstdint>
#include <cstddef>

#define B_    16
#define LQ    30
#define LD    1100
#define DIM   768
#define NH    12
#define DH_   64
#define WINSZ 11
#define WNUM  100
#define NSLOT 32              // 2 docs x 16 batches

typedef __attribute__((ext_vector_type(8))) short short8;
typedef __attribute__((ext_vector_type(4))) float f32x4;

__device__ __forceinline__ void gload_lds16(const void* g, void* l) {
  __builtin_amdgcn_global_load_lds(
      (const __attribute__((address_space(1))) void*)g,
      (__attribute__((address_space(3))) void*)l, 16, 0, 0);
}

// ---------------------------------------------------------------------------
// weights fp32 -> bf16 (once per launch)
// ---------------------------------------------------------------------------
__global__ __launch_bounds__(256) void wconv_kernel(const float* __restrict__ wa,
    const float* __restrict__ wb, __hip_bfloat16* __restrict__ oa,
    __hip_bfloat16* __restrict__ ob) {
  int i = (blockIdx.x * 256 + threadIdx.x) * 4;
  if (i >= DIM * DIM) return;
  float4 va = *reinterpret_cast<const float4*>(wa + i);
  float4 vb = *reinterpret_cast<const float4*>(wb + i);
  union { __hip_bfloat16 h[4]; uint2 u; } pa, pb;
  pa.h[0] = __float2bfloat16(va.x); pa.h[1] = __float2bfloat16(va.y);
  pa.h[2] = __float2bfloat16(va.z); pa.h[3] = __float2bfloat16(va.w);
  pb.h[0] = __float2bfloat16(vb.x); pb.h[1] = __float2bfloat16(vb.y);
  pb.h[2] = __float2bfloat16(vb.z); pb.h[3] = __float2bfloat16(vb.w);
  *reinterpret_cast<uint2*>(oa + i) = pa.u;
  *reinterpret_cast<uint2*>(ob + i) = pb.u;
}

// ---------------------------------------------------------------------------
// prep_q: Xq[row, e] = bf16( emb[q[row], e] * q_mask[row] * 0.125 )
// ---------------------------------------------------------------------------
__global__ __launch_bounds__(256) void prep_q_kernel(const int* __restrict__ q,
    const float* __restrict__ qmask, const float* __restrict__ emb,
    __hip_bfloat16* __restrict__ Xq) {
  int idx = blockIdx.x * 256 + threadIdx.x;        // 480 * 192 quads
  if (idx >= B_ * LQ * (DIM / 4)) return;
  int row = idx / (DIM / 4);
  int c4  = idx % (DIM / 4);
  float m = qmask[row] * 0.125f;
  float4 v = *reinterpret_cast<const float4*>(emb + (size_t)q[row] * DIM + c4 * 4);
  union { __hip_bfloat16 h[4]; uint2 u; } o;
  o.h[0] = __float2bfloat16(v.x * m); o.h[1] = __float2bfloat16(v.y * m);
  o.h[2] = __float2bfloat16(v.z * m); o.h[3] = __float2bfloat16(v.w * m);
  *reinterpret_cast<uint2*>(Xq + (size_t)row * DIM + c4 * 4) = o.u;
}

// ---------------------------------------------------------------------------
// prep_d (both docs): slot s = s0 + r/LD, doc = s>>4, b = s&15, t = r%LD.
// X[r,e] = bf16( (emb[tok,e]*sqrt(D) + pe[t,e]) * mask )   (pe if flag)
// ---------------------------------------------------------------------------
__global__ __launch_bounds__(256) void prep_d_kernel(const int* __restrict__ dpos,
    const int* __restrict__ dneg, const float* __restrict__ dpmask,
    const float* __restrict__ dnmask, const float* __restrict__ emb,
    const int* __restrict__ peflag, __hip_bfloat16* __restrict__ X,
    int s0, int rows) {
  int idx = blockIdx.x * 256 + threadIdx.x;        // rows * 192 quads
  if (idx >= rows * (DIM / 4)) return;
  int r  = idx / (DIM / 4);
  int c4 = idx % (DIM / 4);
  int s = s0 + r / LD;
  int t = r % LD;
  int doc = s >> 4, b = s & 15;
  const int*   di = doc ? dneg   : dpos;
  const float* dm = doc ? dnmask : dpmask;
  int grow = b * LD + t;
  float m = dm[grow];
  float4 v = *reinterpret_cast<const float4*>(emb + (size_t)di[grow] * DIM + c4 * 4);
  if (peflag[0]) {
    int i0 = c4 * 2;                               // pair indices i0, i0+1
    float d0 = expf(-0.023985261387f * (float)i0);
    float d1 = expf(-0.023985261387f * (float)(i0 + 1));
    float s0f, c0f, s1f, c1f;
    sincosf((float)t * d0, &s0f, &c0f);
    sincosf((float)t * d1, &s1f, &c1f);
    v.x = v.x * 27.712812921102035f + s0f;
    v.y = v.y * 27.712812921102035f + c0f;
    v.z = v.z * 27.712812921102035f + s1f;
    v.w = v.w * 27.712812921102035f + c1f;
  }
  union { __hip_bfloat16 h[4]; uint2 u; } o;
  o.h[0] = __float2bfloat16(v.x * m); o.h[1] = __float2bfloat16(v.y * m);
  o.h[2] = __float2bfloat16(v.z * m); o.h[3] = __float2bfloat16(v.w * m);
  *reinterpret_cast<uint2*>(X + (size_t)r * DIM + c4 * 4) = o.u;
}

// ---------------------------------------------------------------------------
// gemm_mfma: C[M,N] = A[M,K](bf16) @ Bt[N,K](bf16)^T, fp32 accum.
// 128x128 tile, BK=32, 4 waves (2x2), mfma_f32_16x16x32_bf16,
// global_load_lds(16B) staging, DOUBLE-BUFFERED prefetch (T3 minimum 2-phase):
// STAGE(t+1) issued before COMPUTE(t); one vmcnt(0)+barrier per K-step.
// K must be a multiple of 64 (here 768 -> 24 tiles). XCD-swizzled 1D grid.
// A/Bt must be readable up to tile-padded rows.
// ---------------------------------------------------------------------------
template <bool OUT_BF16>
__global__ __launch_bounds__(256) void gemm_mfma(const __hip_bfloat16* __restrict__ A,
    const __hip_bfloat16* __restrict__ Bt, void* __restrict__ Cv,
    int M, int N, int K, int tilesX) {
  __shared__ __hip_bfloat16 As[2 * 128 * 32];
  __shared__ __hip_bfloat16 Bs[2 * 128 * 32];
  const int nwg  = gridDim.x;
  const int orig = blockIdx.x;
  const int q8 = nwg >> 3, r8 = nwg & 7;
  const int xcd = orig & 7, pos = orig >> 3;
  const int wgid = (xcd < r8 ? xcd * (q8 + 1) : r8 * (q8 + 1) + (xcd - r8) * q8) + pos;
  const int row0 = (wgid / tilesX) * 128;
  const int col0 = (wgid % tilesX) * 128;

  const int tid  = threadIdx.x;
  const int lane = tid & 63;
  const int wave = tid >> 6;
  const int wr = wave >> 1, wc = wave & 1;
  const int srow = tid >> 2, skoff = (tid & 3) * 8;

  f32x4 acc[4][4] = {};

  const __hip_bfloat16* gA = A  + (size_t)(row0 + srow) * K + skoff;
  const __hip_bfloat16* gB = Bt + (size_t)(col0 + srow) * K + skoff;

  auto STAGE = [&](int buf, int t) {
    const int k0 = t * 32;
    const int lo = buf * 4096;
    gload_lds16(gA + k0,                As + lo + tid * 8);
    gload_lds16(gA + (size_t)64 * K + k0, As + lo + 2048 + tid * 8);
    gload_lds16(gB + k0,                Bs + lo + tid * 8);
    gload_lds16(gB + (size_t)64 * K + k0, Bs + lo + 2048 + tid * 8);
  };
  auto COMPUTE = [&](int buf) {
    const int lo = buf * 4096;
    short8 afrag[4], bfrag[4];
#pragma unroll
    for (int m = 0; m < 4; ++m)
      afrag[m] = *reinterpret_cast<const short8*>(
          &As[lo + (wr * 64 + m * 16 + (lane & 15)) * 32 + (lane >> 4) * 8]);
#pragma unroll
    for (int n = 0; n < 4; ++n)
      bfrag[n] = *reinterpret_cast<const short8*>(
          &Bs[lo + (wc * 64 + n * 16 + (lane & 15)) * 32 + (lane >> 4) * 8]);
#pragma unroll
    for (int m = 0; m < 4; ++m)
#pragma unroll
      for (int n = 0; n < 4; ++n)
        acc[m][n] = __builtin_amdgcn_mfma_f32_16x16x32_bf16(
            afrag[m], bfrag[n], acc[m][n], 0, 0, 0);
  };

  const int nt = K / 32;            // 24 for K=768, even
  STAGE(0, 0);
  __syncthreads();                  // vmcnt(0)+barrier: tile 0 visible
  for (int t = 0; t + 2 < nt; t += 2) {
    STAGE(1, t + 1);                // prefetch while computing buf0
    COMPUTE(0);
    __syncthreads();                // drains vmcnt: tile t+1 visible, buf0 free
    STAGE(0, t + 2);
    COMPUTE(1);
    __syncthreads();
  }
  STAGE(1, nt - 1);
  COMPUTE(0);
  __syncthreads();
  COMPUTE(1);

#pragma unroll
  for (int m = 0; m < 4; ++m) {
    int rb = row0 + wr * 64 + m * 16 + (lane >> 4) * 4;
#pragma unroll
    for (int n = 0; n < 4; ++n) {
      int c = col0 + wc * 64 + n * 16 + (lane & 15);
      f32x4 v = acc[m][n];
#pragma unroll
      for (int j = 0; j < 4; ++j) {
        int r = rb + j;
        if (r < M) {
          if constexpr (OUT_BF16)
            ((__hip_bfloat16*)Cv)[(size_t)r * N + c] = __float2bfloat16(v[j]);
          else
            ((float*)Cv)[(size_t)r * N + c] = v[j];
        }
      }
    }
  }
}

// ---------------------------------------------------------------------------
// attn: one block per (slot_local, w, h), 120 threads = 30 qi x 4 part.
// Q segment in registers from global (L2-hot); D staged in LDS fp32
// (broadcast float4 reads, conflict-free); shfl_xor partial-dot reduce.
// ---------------------------------------------------------------------------
__global__ __launch_bounds__(128) void attn_kernel(const float* __restrict__ Qs,
    const __hip_bfloat16* __restrict__ Y, __hip_bfloat16* __restrict__ ctx, int s0) {
  int blk = blockIdx.x;
  int h  = blk % NH;
  int w  = (blk / NH) % WNUM;
  int sl = blk / (NH * WNUM);
  int b  = (s0 + sl) & 15;          // batch index (doc-independent Q)

  __shared__ float Dl[WINSZ][DH_];

  const __hip_bfloat16* Yb = Y + ((size_t)(sl * LD + w * WINSZ)) * DIM + h * (WINSZ * DH_);
  const float* Qb = Qs + (size_t)b * (LQ * DIM) + h * (LQ * DH_);

  int tid = threadIdx.x;
  int qi = tid >> 2, part = tid & 3;

  if (tid < 88) {
    uint4 raw = *reinterpret_cast<const uint4*>(Yb + tid * 8);
    const __hip_bfloat16* hp = reinterpret_cast<const __hip_bfloat16*>(&raw);
    float* dst = &Dl[0][0] + tid * 8;
#pragma unroll
    for (int j = 0; j < 8; ++j) dst[j] = __bfloat162float(hp[j]);
  }

  float4 qreg[4];
#pragma unroll
  for (int j = 0; j < 4; ++j)
    qreg[j] = *reinterpret_cast<const float4*>(Qb + qi * DH_ + part * 16 + j * 4);
  __syncthreads();

  float dot[WINSZ];
#pragma unroll
  for (int k = 0; k < WINSZ; ++k) {
    const float4* dp = reinterpret_cast<const float4*>(&Dl[k][part * 16]);
    float s = 0.f;
#pragma unroll
    for (int j = 0; j < 4; ++j) {
      float4 dv = dp[j];
      s += qreg[j].x * dv.x + qreg[j].y * dv.y + qreg[j].z * dv.z + qreg[j].w * dv.w;
    }
    dot[k] = s;
  }
#pragma unroll
  for (int k = 0; k < WINSZ; ++k) {
    dot[k] += __shfl_xor(dot[k], 1);
    dot[k] += __shfl_xor(dot[k], 2);
  }
  float mx = -1e30f;
#pragma unroll
  for (int k = 0; k < WINSZ; ++k) mx = fmaxf(mx, dot[k]);
  float sum = 0.f;
#pragma unroll
  for (int k = 0; k < WINSZ; ++k) { dot[k] = expf(dot[k] - mx); sum += dot[k]; }
  float inv = 1.f / sum;

  float4 o[4] = {};
#pragma unroll
  for (int k = 0; k < WINSZ; ++k) {
    float pk = dot[k];
    const float4* dp = reinterpret_cast<const float4*>(&Dl[k][part * 16]);
#pragma unroll
    for (int j = 0; j < 4; ++j) {
      float4 dv = dp[j];
      o[j].x += pk * dv.x; o[j].y += pk * dv.y;
      o[j].z += pk * dv.z; o[j].w += pk * dv.w;
    }
  }
  union { __hip_bfloat16 hh[16]; uint4 v[2]; } pk;
#pragma unroll
  for (int j = 0; j < 4; ++j) {
    pk.hh[j * 4 + 0] = __float2bfloat16(o[j].x * inv);
    pk.hh[j * 4 + 1] = __float2bfloat16(o[j].y * inv);
    pk.hh[j * 4 + 2] = __float2bfloat16(o[j].z * inv);
    pk.hh[j * 4 + 3] = __float2bfloat16(o[j].w * inv);
  }
  __hip_bfloat16* op = ctx + (size_t)(sl * WNUM + w) * (LQ * DIM)
                     + h * (LQ * DH_) + qi * DH_ + part * 16;
  *reinterpret_cast<uint4*>(op)     = pk.v[0];
  *reinterpret_cast<uint4*>(op + 8) = pk.v[1];
}

// ---------------------------------------------------------------------------
extern "C" void kernel_launch(void* const* d_in, const int* in_sizes, int n_in,
                              void* d_out, int out_size, void* d_ws, size_t ws_size,
                              hipStream_t stream) {
  const int*   q      = (const int*)d_in[0];
  const int*   dpos   = (const int*)d_in[1];
  const int*   dneg   = (const int*)d_in[2];
  const float* qmask  = (const float*)d_in[3];
  const float* dpmask = (const float*)d_in[4];
  const float* dnmask = (const float*)d_in[5];
  const int*   peflag = (const int*)d_in[6];
  const float* emb    = (const float*)d_in[7];
  const float* Wlin   = (const float*)d_in[8];
  const float* Wout   = (const float*)d_in[9];
  float* out = (float*)d_out;

  char* ws = (char*)d_ws;
  size_t off = 0;
  auto alloc = [&](size_t bytes) -> char* {
    char* p = ws + off; off += (bytes + 255) & ~(size_t)255; return p;
  };
  __hip_bfloat16* Xq   = (__hip_bfloat16*)alloc((size_t)B_ * LQ * DIM * 2);
  float*          Qsc  = (float*)         alloc((size_t)B_ * LQ * DIM * 4);
  __hip_bfloat16* Wl16 = (__hip_bfloat16*)alloc((size_t)DIM * DIM * 2);
  __hip_bfloat16* Wo16 = (__hip_bfloat16*)alloc((size_t)DIM * DIM * 2);

  // slots per chunk: all 32 (both docs) if ws allows; else halve.
  // buffers tile-padded (+128 rows) so gemm A-overreads stay in-bounds.
  int SC = NSLOT;
  while (SC > 1) {
    size_t need = off
        + ((size_t)SC * LD + 128) * DIM * 2 * 2                 // X + Y
        + ((size_t)SC * WNUM * LQ + 128) * DIM * 2 + (1u << 20);// ctx
    if (need <= ws_size) break;
    SC >>= 1;
  }
  __hip_bfloat16* X   = (__hip_bfloat16*)alloc(((size_t)SC * LD + 128) * DIM * 2);
  __hip_bfloat16* Y   = (__hip_bfloat16*)alloc(((size_t)SC * LD + 128) * DIM * 2);
  __hip_bfloat16* ctx = (__hip_bfloat16*)alloc(((size_t)SC * WNUM * LQ + 128) * DIM * 2);

  wconv_kernel<<<(DIM * DIM / 4 + 255) / 256, 256, 0, stream>>>(Wlin, Wout, Wl16, Wo16);
  prep_q_kernel<<<(B_ * LQ * (DIM / 4) + 255) / 256, 256, 0, stream>>>(q, qmask, emb, Xq);
  {
    int tilesX = DIM / 128, tilesY = (B_ * LQ + 127) / 128;
    gemm_mfma<false><<<tilesX * tilesY, 256, 0, stream>>>(
        Xq, Wl16, Qsc, B_ * LQ, DIM, DIM, tilesX);
  }

  for (int s0 = 0; s0 < NSLOT; s0 += SC) {
    const int rowsX = SC * LD;           // 35200 at SC=32
    const int rowsC = SC * WNUM * LQ;    // 96000 at SC=32
    prep_d_kernel<<<(rowsX * (DIM / 4) + 255) / 256, 256, 0, stream>>>(
        dpos, dneg, dpmask, dnmask, emb, peflag, X, s0, rowsX);
    {
      int tilesX = DIM / 128, tilesY = (rowsX + 127) / 128;
      gemm_mfma<true><<<tilesX * tilesY, 256, 0, stream>>>(
          X, Wl16, Y, rowsX, DIM, DIM, tilesX);
    }
    attn_kernel<<<SC * WNUM * NH, 120, 0, stream>>>(Qsc, Y, ctx, s0);
    {
      int tilesX = DIM / 128, tilesY = (rowsC + 127) / 128;
      gemm_mfma<false><<<tilesX * tilesY, 256, 0, stream>>>(
          ctx, Wo16, out + (size_t)s0 * WNUM * LQ * DIM, rowsC, DIM, DIM, tilesX);
    }
  }
}